// Round 24
// baseline (160.473 us; speedup 1.0000x reference)
//
#include <hip/hip_runtime.h>

// Problem constants (fixed by setup_inputs)
#define BB 8
#define CIN 64
#define COUT 64
#define NN 2048
#define TT 13
#define KTT 3
#define LL 11
#define CL 704                         // COUT*LL
#define HP_SIZE 11534336LL             // B*COUT*N*L

// ws layout (bytes): fbuf 65536 | maxf 32 | tab4 262144 | w0pk 24576 | Apan
#define WS_TAB_OFF 65568ULL
#define WS_W0PK_OFF 327712ULL
#define WS_APAN_OFF 352288ULL

typedef _Float16 f16;
typedef __attribute__((ext_vector_type(8))) _Float16 f16x8;
typedef __attribute__((ext_vector_type(2))) _Float16 f16x2;
typedef __attribute__((ext_vector_type(4))) float f32x4;

__device__ __forceinline__ unsigned int pk16(float a, float b) {
  f16 ha = (f16)a, hb = (f16)b;                    // RTN converts
  unsigned short ua = __builtin_bit_cast(unsigned short, ha);
  unsigned short ub = __builtin_bit_cast(unsigned short, hb);
  return (unsigned int)ua | ((unsigned int)ub << 16);
}
__device__ __forceinline__ f16x2 as_h2(unsigned int u) {
  return __builtin_bit_cast(f16x2, u);
}

// ---------------------------------------------------------------------------
// Kernel 0: pack w0 into ci-pair v2f16 form, once.
// ---------------------------------------------------------------------------
__global__ __launch_bounds__(256) void k_pack(const float* __restrict__ w0,
                                              unsigned int* __restrict__ w0pk_g) {
  int tid = blockIdx.x * 256 + threadIdx.x;        // 6144 total
  int c = tid & 63, r = tid >> 6;                  // r = cip*3+kt, 0..95
  int kt = r % 3, cip = r / 3;
  float ev = w0[c * 192 + cip * 6 + kt];
  float od = w0[c * 192 + cip * 6 + 3 + kt];
  w0pk_g[r * 64 + c] = pk16(ev, od);
}

// ---------------------------------------------------------------------------
// Kernel 1: conv0 via v_dot2_f32_f16 -> fp16 A panels (16-row-frag layout) + f.
// R24: w0pk read DIRECTLY from global (24 KB chip-hot, L1/L2-resident,
// per-lane coalesced, depth-1 register prefetch) -> conv LDS 27648 B ->
// 4 blocks/CU = 32 waves (HW max TLP for the wave-uniform x broadcasts).
// A panel: Apan[(b*11+mt)*64+ks] tile of 2048 f16 = [fr4][lane64][kk8].
// ---------------------------------------------------------------------------
__global__ __launch_bounds__(512, 8) void k_conv(
    const float* __restrict__ x, const unsigned int* __restrict__ w0pk_g,
    const float* __restrict__ b0, const float* __restrict__ w1,
    f16* __restrict__ Apan, float* __restrict__ f) {
  __shared__ unsigned int xspk[32 * 8 * 16];   // 16384 B
  __shared__ f16 As[704 * 8];                  // 11264 B  (total 27648)
  const int tid = threadIdx.x;
  const int b = blockIdx.x >> 8;
  const int n0 = (blockIdx.x & 255) << 3;

#pragma unroll
  for (int i = 0; i < 7; ++i) {
    int task = i * 512 + tid;                  // 3328 total
    if (task < 3328) {
      int cip = task / 104, rem = task - cip * 104;
      long long base = (long long)(b * 64 + 2 * cip) * 26624 + n0 * 13 + rem;
      float ev = x[base];
      float od = x[base + 26624];
      int n = rem / 13, t = rem - n * 13;
      xspk[(cip * 8 + n) * 16 + t] = pk16(ev, od);
    }
  }
  __syncthreads();

  const int c = tid & 63, w = tid >> 6;
  float acc[11];
  const float bias = b0[c];
#pragma unroll
  for (int l = 0; l < 11; ++l) acc[l] = bias;

  // depth-1 register prefetch of the packed w0 trio (global, coalesced)
  f16x2 wk0 = as_h2(w0pk_g[0 * 64 + c]);
  f16x2 wk1 = as_h2(w0pk_g[1 * 64 + c]);
  f16x2 wk2 = as_h2(w0pk_g[2 * 64 + c]);

  for (int cip = 0; cip < 32; ++cip) {
    f16x2 nk0 = wk0, nk1 = wk1, nk2 = wk2;
    if (cip < 31) {
      nk0 = as_h2(w0pk_g[((cip + 1) * 3 + 0) * 64 + c]);
      nk1 = as_h2(w0pk_g[((cip + 1) * 3 + 1) * 64 + c]);
      nk2 = as_h2(w0pk_g[((cip + 1) * 3 + 2) * 64 + c]);
    }
    const unsigned int* xr = &xspk[(cip * 8 + w) * 16];
    uint4 xa = *(const uint4*)xr;
    uint4 xb = *(const uint4*)(xr + 4);
    uint4 xc = *(const uint4*)(xr + 8);
    unsigned int x13[13] = {xa.x, xa.y, xa.z, xa.w, xb.x, xb.y, xb.z, xb.w,
                            xc.x, xc.y, xc.z, xc.w, xr[12]};
#pragma unroll
    for (int l = 0; l < 11; ++l) {
      acc[l] = __builtin_amdgcn_fdot2(as_h2(x13[l]), wk0, acc[l], false);
      acc[l] = __builtin_amdgcn_fdot2(as_h2(x13[l + 1]), wk1, acc[l], false);
      acc[l] = __builtin_amdgcn_fdot2(as_h2(x13[l + 2]), wk2, acc[l], false);
    }
    wk0 = nk0; wk1 = nk1; wk2 = nk2;
  }

  float p = 0.f;
#pragma unroll
  for (int l = 0; l < 11; ++l) p = fmaf(acc[l], w1[c * 11 + l], p);
#pragma unroll
  for (int off = 32; off; off >>= 1) p += __shfl_xor(p, off, 64);
  if (c == 0) f[b * 2048 + n0 + w] = p;

#pragma unroll
  for (int l = 0; l < 11; ++l) As[(c * 11 + l) * 8 + w] = (f16)acc[l];
  __syncthreads();

  // panel write: this block covers ks, kgrp, kk = 0..7 (= w dim in As)
  const int ks = n0 >> 5, kgrp = (n0 >> 3) & 3;
#pragma unroll
  for (int i = 0; i < 2; ++i) {
    int m = i * 512 + tid;
    if (m < 704) {
      uint4 v = *(const uint4*)&As[m * 8];     // linear 16B/lane, conflict-free
      int mt = m >> 6, fr = (m >> 4) & 3, r16 = m & 15;
      long long base = ((long long)(b * 11 + mt) * 64 + ks) * 2048 +
                       fr * 512 + (kgrp * 16 + r16) * 8;
      *(uint4*)&Apan[base] = v;
    }
  }
}

// ---------------------------------------------------------------------------
// Kernel 2: per-batch max of f
// ---------------------------------------------------------------------------
__global__ __launch_bounds__(256) void k_maxf(const float* __restrict__ f,
                                              float* __restrict__ maxf) {
  const int b = blockIdx.x, tid = threadIdx.x;
  float m = -1e30f;
  for (int i = tid; i < 2048; i += 256) m = fmaxf(m, f[b * 2048 + i]);
#pragma unroll
  for (int off = 32; off; off >>= 1) m = fmaxf(m, __shfl_xor(m, off, 64));
  __shared__ float red[4];
  if ((tid & 63) == 0) red[tid >> 6] = m;
  __syncthreads();
  if (tid == 0) maxf[b] = fmaxf(fmaxf(red[0], red[1]), fmaxf(red[2], red[3]));
}

// ---------------------------------------------------------------------------
// Kernel 3: softmax row sums + exp-factor table tab4 = (En, E2n, Rq, Sq).
// att[n][q] = max(En_n*Rq_q, E2n_n*Sq_q)  (exact: pos-branch wins iff s>=0)
// ---------------------------------------------------------------------------
__global__ __launch_bounds__(256) void k_rowsum(const float* __restrict__ f,
                                                const float* __restrict__ maxf,
                                                float4* __restrict__ tab4) {
  __shared__ float fs[2048];
  const int b = blockIdx.x >> 9;
  const int q0 = (blockIdx.x & 511) << 2;
  const int tid = threadIdx.x;
#pragma unroll
  for (int i = 0; i < 8; ++i) fs[i * 256 + tid] = f[b * 2048 + i * 256 + tid];
  __syncthreads();
  const int lane = tid & 63, wid = tid >> 6;
  const int q = q0 + wid;
  const float fq = fs[q];
  const float mb = maxf[b];
  float t = fq + mb;
  const float m = t >= 0.f ? t : 0.2f * t;
  float sum = 0.f;
  for (int j = lane; j < 2048; j += 64) {
    float v = fq + fs[j];
    v = v >= 0.f ? v : 0.2f * v;
    sum += __expf(v - m);
  }
#pragma unroll
  for (int off = 32; off; off >>= 1) sum += __shfl_xor(sum, off, 64);
  if (lane == 0) {
    float rq = 1.0f / sum;
    float En = __expf(fq - mb);
    float E2 = __expf(0.2f * fq);
    float Rq = t >= 0.f ? rq : rq * __expf(0.8f * t);
    float Sq = rq * __expf(0.2f * fq - m);
    tab4[b * 2048 + q] = make_float4(En, E2, Rq, Sq);
  }
}

// ---------------------------------------------------------------------------
// Kernel 4: barrier-free 16x16x32 fp16 MFMA GEMM (R22: hoisted B-build +
// single setprio(1) burst of 16 MFMAs).
// ---------------------------------------------------------------------------
__global__ __launch_bounds__(256, 3) void k_gemm(const f16* __restrict__ Apan,
                                                 const float4* __restrict__ tab4,
                                                 float* __restrict__ att,
                                                 float* __restrict__ out) {
  __shared__ __align__(16) float2 Etab[2048];   // 16 KB, read-only after stage

  const int p = blockIdx.x;
  const int g = p % 88, qt = p / 88;
  const int b = g / 11, mt = g % 11;

  const int tid = threadIdx.x;
  const int qw = tid >> 6, lane = tid & 63;
  const int l15 = lane & 15, l4 = lane >> 4;

  const f16* Ab = Apan + ((long long)(b * 11 + mt) * 64) * 2048 + lane * 8;
  const float4* tb = tab4 + (long long)b * NN;

  // stage Etab (16 KB)
#pragma unroll
  for (int i = 0; i < 8; ++i) {
    int idx = i * 256 + tid;
    float4 v = tb[idx];
    Etab[idx] = make_float2(v.x, v.y);
  }
  // per-nf q-side factors (q fixed per lane per nf)
  const int q0 = qt * 256 + qw * 64 + l15;
  float Rq0, Sq0, Rq1, Sq1, Rq2, Sq2, Rq3, Sq3;
  { float4 t4 = tb[q0];      Rq0 = t4.z; Sq0 = t4.w; }
  { float4 t4 = tb[q0 + 16]; Rq1 = t4.z; Sq1 = t4.w; }
  { float4 t4 = tb[q0 + 32]; Rq2 = t4.z; Sq2 = t4.w; }
  { float4 t4 = tb[q0 + 48]; Rq3 = t4.z; Sq3 = t4.w; }
  __syncthreads();   // Etab ready; ONLY barrier in the kernel

  f32x4 acc[4][4];
#pragma unroll
  for (int fr = 0; fr < 4; ++fr)
#pragma unroll
    for (int nf = 0; nf < 4; ++nf) acc[fr][nf] = (f32x4){0.f, 0.f, 0.f, 0.f};

  // A-load pipeline: current tile in c0..c3, next prefetched into n0..n3
  f16x8 c0 = *(const f16x8*)(Ab);
  f16x8 c1 = *(const f16x8*)(Ab + 512);
  f16x8 c2 = *(const f16x8*)(Ab + 1024);
  f16x8 c3 = *(const f16x8*)(Ab + 1536);

  for (int ks = 0; ks < 64; ++ks) {
    f16x8 n0 = c0, n1 = c1, n2 = c2, n3 = c3;
    if (ks < 63) {
      const f16* at = Ab + (ks + 1) * 2048;
      n0 = *(const f16x8*)(at);
      n1 = *(const f16x8*)(at + 512);
      n2 = *(const f16x8*)(at + 1024);
      n3 = *(const f16x8*)(at + 1536);
    }
    // lane's 8 n-values of the exp-factor table (broadcast within 16-group)
    const int nb = ks * 32 + l4 * 8;
    const float4* ep = (const float4*)&Etab[nb];
    float4 e0 = ep[0], e1 = ep[1], e2 = ep[2], e3 = ep[3];
    float En[8] = {e0.x, e0.z, e1.x, e1.z, e2.x, e2.z, e3.x, e3.z};
    float E2[8] = {e0.y, e0.w, e1.y, e1.w, e2.y, e2.w, e3.y, e3.w};
    const bool owned = ((ks * 11) >> 6) == mt;   // block-uniform
    const long long abase = ((long long)(b * 2048 + nb)) * 2048 + q0;

    // ---- build ALL 4 B fragments (independent chains -> VALU ILP) ----
    f16x8 bv0, bv1, bv2, bv3;
    float vf[4][8];
#pragma unroll
    for (int u = 0; u < 8; ++u) {
      float v0 = fmaxf(En[u] * Rq0, E2[u] * Sq0);
      float v1 = fmaxf(En[u] * Rq1, E2[u] * Sq1);
      float v2 = fmaxf(En[u] * Rq2, E2[u] * Sq2);
      float v3 = fmaxf(En[u] * Rq3, E2[u] * Sq3);
      vf[0][u] = v0; vf[1][u] = v1; vf[2][u] = v2; vf[3][u] = v3;
      bv0[u] = (f16)v0; bv1[u] = (f16)v1; bv2[u] = (f16)v2; bv3[u] = (f16)v3;
    }
    if (owned) {
#pragma unroll
      for (int nf = 0; nf < 4; ++nf) {
        float* ap = att + abase + nf * 16;
#pragma unroll
        for (int u = 0; u < 8; ++u) ap[(long long)u * 2048] = vf[nf][u];
      }
    }
    // ---- 16 back-to-back MFMAs in one prioritized burst ----
    __builtin_amdgcn_s_setprio(1);
    acc[0][0] = __builtin_amdgcn_mfma_f32_16x16x32_f16(c0, bv0, acc[0][0], 0, 0, 0);
    acc[1][0] = __builtin_amdgcn_mfma_f32_16x16x32_f16(c1, bv0, acc[1][0], 0, 0, 0);
    acc[2][0] = __builtin_amdgcn_mfma_f32_16x16x32_f16(c2, bv0, acc[2][0], 0, 0, 0);
    acc[3][0] = __builtin_amdgcn_mfma_f32_16x16x32_f16(c3, bv0, acc[3][0], 0, 0, 0);
    acc[0][1] = __builtin_amdgcn_mfma_f32_16x16x32_f16(c0, bv1, acc[0][1], 0, 0, 0);
    acc[1][1] = __builtin_amdgcn_mfma_f32_16x16x32_f16(c1, bv1, acc[1][1], 0, 0, 0);
    acc[2][1] = __builtin_amdgcn_mfma_f32_16x16x32_f16(c2, bv1, acc[2][1], 0, 0, 0);
    acc[3][1] = __builtin_amdgcn_mfma_f32_16x16x32_f16(c3, bv1, acc[3][1], 0, 0, 0);
    acc[0][2] = __builtin_amdgcn_mfma_f32_16x16x32_f16(c0, bv2, acc[0][2], 0, 0, 0);
    acc[1][2] = __builtin_amdgcn_mfma_f32_16x16x32_f16(c1, bv2, acc[1][2], 0, 0, 0);
    acc[2][2] = __builtin_amdgcn_mfma_f32_16x16x32_f16(c2, bv2, acc[2][2], 0, 0, 0);
    acc[3][2] = __builtin_amdgcn_mfma_f32_16x16x32_f16(c3, bv2, acc[3][2], 0, 0, 0);
    acc[0][3] = __builtin_amdgcn_mfma_f32_16x16x32_f16(c0, bv3, acc[0][3], 0, 0, 0);
    acc[1][3] = __builtin_amdgcn_mfma_f32_16x16x32_f16(c1, bv3, acc[1][3], 0, 0, 0);
    acc[2][3] = __builtin_amdgcn_mfma_f32_16x16x32_f16(c2, bv3, acc[2][3], 0, 0, 0);
    acc[3][3] = __builtin_amdgcn_mfma_f32_16x16x32_f16(c3, bv3, acc[3][3], 0, 0, 0);
    __builtin_amdgcn_s_setprio(0);

    c0 = n0; c1 = n1; c2 = n2; c3 = n3;
  }

  // epilogue: C/D layout col(q)=lane&15, row(m)=(lane>>4)*4+r
  float* ob = out + (long long)b * COUT * NN * LL;
#pragma unroll
  for (int fr = 0; fr < 4; ++fr) {
#pragma unroll
    for (int r = 0; r < 4; ++r) {
      int m = mt * 64 + fr * 16 + l4 * 4 + r;
      int c = m / 11, l2 = m - c * 11;
      float* orow = ob + (long long)c * NN * LL + l2;
#pragma unroll
      for (int nf = 0; nf < 4; ++nf) {
        int q = q0 + nf * 16;
        orow[(long long)q * LL] = acc[fr][nf][r];
      }
    }
  }
}

// ---------------------------------------------------------------------------
extern "C" void kernel_launch(void* const* d_in, const int* in_sizes, int n_in,
                              void* d_out, int out_size, void* d_ws, size_t ws_size,
                              hipStream_t stream) {
  const float* x  = (const float*)d_in[0];
  const float* w0 = (const float*)d_in[1];
  const float* b0 = (const float*)d_in[2];
  const float* w1 = (const float*)d_in[3];

  float* fbuf = (float*)d_ws;                                   // 16384 f
  float* maxf = fbuf + BB * NN;                                 // 8 f
  float4* tab4 = (float4*)((char*)d_ws + WS_TAB_OFF);           // 16384 float4
  unsigned int* w0pk_g = (unsigned int*)((char*)d_ws + WS_W0PK_OFF);  // 24 KB
  f16* Apan = (f16*)((char*)d_ws + WS_APAN_OFF);                // 23.07 MB

  float* hp  = (float*)d_out;
  float* att = hp + HP_SIZE;

  k_pack<<<dim3(24), dim3(256), 0, stream>>>(w0, w0pk_g);
  k_conv<<<dim3(BB * 256), dim3(512), 0, stream>>>(x, w0pk_g, b0, w1, Apan, fbuf);
  k_maxf<<<dim3(BB), dim3(256), 0, stream>>>(fbuf, maxf);
  k_rowsum<<<dim3(BB * 512), dim3(256), 0, stream>>>(fbuf, maxf, tab4);
  k_gemm<<<dim3(704), dim3(256), 0, stream>>>(Apan, tab4, att, hp);
}

// Round 25
// 150.962 us; speedup vs baseline: 1.0630x; 1.0630x over previous
//
#include <hip/hip_runtime.h>

// Problem constants (fixed by setup_inputs)
#define BB 8
#define CIN 64
#define COUT 64
#define NN 2048
#define TT 13
#define KTT 3
#define LL 11
#define CL 704                         // COUT*LL
#define HP_SIZE 11534336LL             // B*COUT*N*L

// ws layout (bytes): fbuf 65536 | maxf 32 | tab4 262144 | w0pk 24576 | Apan
#define WS_TAB_OFF 65568ULL
#define WS_W0PK_OFF 327712ULL
#define WS_APAN_OFF 352288ULL

typedef _Float16 f16;
typedef __attribute__((ext_vector_type(8))) _Float16 f16x8;
typedef __attribute__((ext_vector_type(2))) _Float16 f16x2;
typedef __attribute__((ext_vector_type(4))) float f32x4;

__device__ __forceinline__ unsigned int pk16(float a, float b) {
  f16 ha = (f16)a, hb = (f16)b;                    // RTN converts
  unsigned short ua = __builtin_bit_cast(unsigned short, ha);
  unsigned short ub = __builtin_bit_cast(unsigned short, hb);
  return (unsigned int)ua | ((unsigned int)ub << 16);
}
__device__ __forceinline__ f16x2 as_h2(unsigned int u) {
  return __builtin_bit_cast(f16x2, u);
}

// ---------------------------------------------------------------------------
// Kernel 0: pack w0 into ci-pair v2f16 form, once.
// ---------------------------------------------------------------------------
__global__ __launch_bounds__(256) void k_pack(const float* __restrict__ w0,
                                              unsigned int* __restrict__ w0pk_g) {
  int tid = blockIdx.x * 256 + threadIdx.x;        // 6144 total
  int c = tid & 63, r = tid >> 6;                  // r = cip*3+kt, 0..95
  int kt = r % 3, cip = r / 3;
  float ev = w0[c * 192 + cip * 6 + kt];
  float od = w0[c * 192 + cip * 6 + 3 + kt];
  w0pk_g[r * 64 + c] = pk16(ev, od);
}

// ---------------------------------------------------------------------------
// Kernel 1: conv0 via v_dot2_f32_f16 -> fp16 A panels (16-row-frag layout) + f.
// R23 champion: LDS w0 (per-lane reads) + packed-x staging + pad-free As
// -> LDS 52224 B -> 3 blocks/CU (24 waves of latency hiding).
// A panel: Apan[(b*11+mt)*64+ks] tile of 2048 f16 = [fr4][lane64][kk8].
// ---------------------------------------------------------------------------
__global__ __launch_bounds__(512, 6) void k_conv(
    const float* __restrict__ x, const unsigned int* __restrict__ w0pk_g,
    const float* __restrict__ b0, const float* __restrict__ w1,
    f16* __restrict__ Apan, float* __restrict__ f) {
  __shared__ unsigned int w0pk[96 * 64];       // 24576 B
  __shared__ unsigned int xspk[32 * 8 * 16];   // 16384 B
  __shared__ f16 As[704 * 8];                  // 11264 B  (total 52224)
  const int tid = threadIdx.x;
  const int b = blockIdx.x >> 8;
  const int n0 = (blockIdx.x & 255) << 3;

#pragma unroll
  for (int i = 0; i < 12; ++i) w0pk[i * 512 + tid] = w0pk_g[i * 512 + tid];

#pragma unroll
  for (int i = 0; i < 7; ++i) {
    int task = i * 512 + tid;                  // 3328 total
    if (task < 3328) {
      int cip = task / 104, rem = task - cip * 104;
      long long base = (long long)(b * 64 + 2 * cip) * 26624 + n0 * 13 + rem;
      float ev = x[base];
      float od = x[base + 26624];
      int n = rem / 13, t = rem - n * 13;
      xspk[(cip * 8 + n) * 16 + t] = pk16(ev, od);
    }
  }
  __syncthreads();

  const int c = tid & 63, w = tid >> 6;
  float acc[11];
  const float bias = b0[c];
#pragma unroll
  for (int l = 0; l < 11; ++l) acc[l] = bias;

  for (int cip = 0; cip < 32; ++cip) {
    const unsigned int* xr = &xspk[(cip * 8 + w) * 16];
    uint4 xa = *(const uint4*)xr;
    uint4 xb = *(const uint4*)(xr + 4);
    uint4 xc = *(const uint4*)(xr + 8);
    unsigned int x13[13] = {xa.x, xa.y, xa.z, xa.w, xb.x, xb.y, xb.z, xb.w,
                            xc.x, xc.y, xc.z, xc.w, xr[12]};
    f16x2 wk0 = as_h2(w0pk[(cip * 3 + 0) * 64 + c]);
    f16x2 wk1 = as_h2(w0pk[(cip * 3 + 1) * 64 + c]);
    f16x2 wk2 = as_h2(w0pk[(cip * 3 + 2) * 64 + c]);
#pragma unroll
    for (int l = 0; l < 11; ++l) {
      acc[l] = __builtin_amdgcn_fdot2(as_h2(x13[l]), wk0, acc[l], false);
      acc[l] = __builtin_amdgcn_fdot2(as_h2(x13[l + 1]), wk1, acc[l], false);
      acc[l] = __builtin_amdgcn_fdot2(as_h2(x13[l + 2]), wk2, acc[l], false);
    }
  }

  float p = 0.f;
#pragma unroll
  for (int l = 0; l < 11; ++l) p = fmaf(acc[l], w1[c * 11 + l], p);
#pragma unroll
  for (int off = 32; off; off >>= 1) p += __shfl_xor(p, off, 64);
  if (c == 0) f[b * 2048 + n0 + w] = p;

#pragma unroll
  for (int l = 0; l < 11; ++l) As[(c * 11 + l) * 8 + w] = (f16)acc[l];
  __syncthreads();

  // panel write: this block covers ks, kgrp, kk = 0..7 (= w dim in As)
  const int ks = n0 >> 5, kgrp = (n0 >> 3) & 3;
#pragma unroll
  for (int i = 0; i < 2; ++i) {
    int m = i * 512 + tid;
    if (m < 704) {
      uint4 v = *(const uint4*)&As[m * 8];     // linear 16B/lane, conflict-free
      int mt = m >> 6, fr = (m >> 4) & 3, r16 = m & 15;
      long long base = ((long long)(b * 11 + mt) * 64 + ks) * 2048 +
                       fr * 512 + (kgrp * 16 + r16) * 8;
      *(uint4*)&Apan[base] = v;
    }
  }
}

// ---------------------------------------------------------------------------
// Kernel 2: per-batch max of f
// ---------------------------------------------------------------------------
__global__ __launch_bounds__(256) void k_maxf(const float* __restrict__ f,
                                              float* __restrict__ maxf) {
  const int b = blockIdx.x, tid = threadIdx.x;
  float m = -1e30f;
  for (int i = tid; i < 2048; i += 256) m = fmaxf(m, f[b * 2048 + i]);
#pragma unroll
  for (int off = 32; off; off >>= 1) m = fmaxf(m, __shfl_xor(m, off, 64));
  __shared__ float red[4];
  if ((tid & 63) == 0) red[tid >> 6] = m;
  __syncthreads();
  if (tid == 0) maxf[b] = fmaxf(fmaxf(red[0], red[1]), fmaxf(red[2], red[3]));
}

// ---------------------------------------------------------------------------
// Kernel 3: softmax row sums + exp-factor table tab4 = (En, E2n, Rq, Sq).
// att[n][q] = max(En_n*Rq_q, E2n_n*Sq_q)  (exact: pos-branch wins iff s>=0)
// ---------------------------------------------------------------------------
__global__ __launch_bounds__(256) void k_rowsum(const float* __restrict__ f,
                                                const float* __restrict__ maxf,
                                                float4* __restrict__ tab4) {
  __shared__ float fs[2048];
  const int b = blockIdx.x >> 9;
  const int q0 = (blockIdx.x & 511) << 2;
  const int tid = threadIdx.x;
#pragma unroll
  for (int i = 0; i < 8; ++i) fs[i * 256 + tid] = f[b * 2048 + i * 256 + tid];
  __syncthreads();
  const int lane = tid & 63, wid = tid >> 6;
  const int q = q0 + wid;
  const float fq = fs[q];
  const float mb = maxf[b];
  float t = fq + mb;
  const float m = t >= 0.f ? t : 0.2f * t;
  float sum = 0.f;
  for (int j = lane; j < 2048; j += 64) {
    float v = fq + fs[j];
    v = v >= 0.f ? v : 0.2f * v;
    sum += __expf(v - m);
  }
#pragma unroll
  for (int off = 32; off; off >>= 1) sum += __shfl_xor(sum, off, 64);
  if (lane == 0) {
    float rq = 1.0f / sum;
    float En = __expf(fq - mb);
    float E2 = __expf(0.2f * fq);
    float Rq = t >= 0.f ? rq : rq * __expf(0.8f * t);
    float Sq = rq * __expf(0.2f * fq - m);
    tab4[b * 2048 + q] = make_float4(En, E2, Rq, Sq);
  }
}

// ---------------------------------------------------------------------------
// Kernel 4: barrier-free 16x16x32 fp16 MFMA GEMM (champion: hoisted B-build
// + single setprio(1) burst of 16 MFMAs; XCD-grouped grid; fused att stores).
// ---------------------------------------------------------------------------
__global__ __launch_bounds__(256, 3) void k_gemm(const f16* __restrict__ Apan,
                                                 const float4* __restrict__ tab4,
                                                 float* __restrict__ att,
                                                 float* __restrict__ out) {
  __shared__ __align__(16) float2 Etab[2048];   // 16 KB, read-only after stage

  const int p = blockIdx.x;
  const int g = p % 88, qt = p / 88;
  const int b = g / 11, mt = g % 11;

  const int tid = threadIdx.x;
  const int qw = tid >> 6, lane = tid & 63;
  const int l15 = lane & 15, l4 = lane >> 4;

  const f16* Ab = Apan + ((long long)(b * 11 + mt) * 64) * 2048 + lane * 8;
  const float4* tb = tab4 + (long long)b * NN;

  // stage Etab (16 KB)
#pragma unroll
  for (int i = 0; i < 8; ++i) {
    int idx = i * 256 + tid;
    float4 v = tb[idx];
    Etab[idx] = make_float2(v.x, v.y);
  }
  // per-nf q-side factors (q fixed per lane per nf)
  const int q0 = qt * 256 + qw * 64 + l15;
  float Rq0, Sq0, Rq1, Sq1, Rq2, Sq2, Rq3, Sq3;
  { float4 t4 = tb[q0];      Rq0 = t4.z; Sq0 = t4.w; }
  { float4 t4 = tb[q0 + 16]; Rq1 = t4.z; Sq1 = t4.w; }
  { float4 t4 = tb[q0 + 32]; Rq2 = t4.z; Sq2 = t4.w; }
  { float4 t4 = tb[q0 + 48]; Rq3 = t4.z; Sq3 = t4.w; }
  __syncthreads();   // Etab ready; ONLY barrier in the kernel

  f32x4 acc[4][4];
#pragma unroll
  for (int fr = 0; fr < 4; ++fr)
#pragma unroll
    for (int nf = 0; nf < 4; ++nf) acc[fr][nf] = (f32x4){0.f, 0.f, 0.f, 0.f};

  // A-load pipeline: current tile in c0..c3, next prefetched into n0..n3
  f16x8 c0 = *(const f16x8*)(Ab);
  f16x8 c1 = *(const f16x8*)(Ab + 512);
  f16x8 c2 = *(const f16x8*)(Ab + 1024);
  f16x8 c3 = *(const f16x8*)(Ab + 1536);

  for (int ks = 0; ks < 64; ++ks) {
    f16x8 n0 = c0, n1 = c1, n2 = c2, n3 = c3;
    if (ks < 63) {
      const f16* at = Ab + (ks + 1) * 2048;
      n0 = *(const f16x8*)(at);
      n1 = *(const f16x8*)(at + 512);
      n2 = *(const f16x8*)(at + 1024);
      n3 = *(const f16x8*)(at + 1536);
    }
    // lane's 8 n-values of the exp-factor table (broadcast within 16-group)
    const int nb = ks * 32 + l4 * 8;
    const float4* ep = (const float4*)&Etab[nb];
    float4 e0 = ep[0], e1 = ep[1], e2 = ep[2], e3 = ep[3];
    float En[8] = {e0.x, e0.z, e1.x, e1.z, e2.x, e2.z, e3.x, e3.z};
    float E2[8] = {e0.y, e0.w, e1.y, e1.w, e2.y, e2.w, e3.y, e3.w};
    const bool owned = ((ks * 11) >> 6) == mt;   // block-uniform
    const long long abase = ((long long)(b * 2048 + nb)) * 2048 + q0;

    // ---- build ALL 4 B fragments (independent chains -> VALU ILP) ----
    f16x8 bv0, bv1, bv2, bv3;
    float vf[4][8];
#pragma unroll
    for (int u = 0; u < 8; ++u) {
      float v0 = fmaxf(En[u] * Rq0, E2[u] * Sq0);
      float v1 = fmaxf(En[u] * Rq1, E2[u] * Sq1);
      float v2 = fmaxf(En[u] * Rq2, E2[u] * Sq2);
      float v3 = fmaxf(En[u] * Rq3, E2[u] * Sq3);
      vf[0][u] = v0; vf[1][u] = v1; vf[2][u] = v2; vf[3][u] = v3;
      bv0[u] = (f16)v0; bv1[u] = (f16)v1; bv2[u] = (f16)v2; bv3[u] = (f16)v3;
    }
    if (owned) {
#pragma unroll
      for (int nf = 0; nf < 4; ++nf) {
        float* ap = att + abase + nf * 16;
#pragma unroll
        for (int u = 0; u < 8; ++u) ap[(long long)u * 2048] = vf[nf][u];
      }
    }
    // ---- 16 back-to-back MFMAs in one prioritized burst ----
    __builtin_amdgcn_s_setprio(1);
    acc[0][0] = __builtin_amdgcn_mfma_f32_16x16x32_f16(c0, bv0, acc[0][0], 0, 0, 0);
    acc[1][0] = __builtin_amdgcn_mfma_f32_16x16x32_f16(c1, bv0, acc[1][0], 0, 0, 0);
    acc[2][0] = __builtin_amdgcn_mfma_f32_16x16x32_f16(c2, bv0, acc[2][0], 0, 0, 0);
    acc[3][0] = __builtin_amdgcn_mfma_f32_16x16x32_f16(c3, bv0, acc[3][0], 0, 0, 0);
    acc[0][1] = __builtin_amdgcn_mfma_f32_16x16x32_f16(c0, bv1, acc[0][1], 0, 0, 0);
    acc[1][1] = __builtin_amdgcn_mfma_f32_16x16x32_f16(c1, bv1, acc[1][1], 0, 0, 0);
    acc[2][1] = __builtin_amdgcn_mfma_f32_16x16x32_f16(c2, bv1, acc[2][1], 0, 0, 0);
    acc[3][1] = __builtin_amdgcn_mfma_f32_16x16x32_f16(c3, bv1, acc[3][1], 0, 0, 0);
    acc[0][2] = __builtin_amdgcn_mfma_f32_16x16x32_f16(c0, bv2, acc[0][2], 0, 0, 0);
    acc[1][2] = __builtin_amdgcn_mfma_f32_16x16x32_f16(c1, bv2, acc[1][2], 0, 0, 0);
    acc[2][2] = __builtin_amdgcn_mfma_f32_16x16x32_f16(c2, bv2, acc[2][2], 0, 0, 0);
    acc[3][2] = __builtin_amdgcn_mfma_f32_16x16x32_f16(c3, bv2, acc[3][2], 0, 0, 0);
    acc[0][3] = __builtin_amdgcn_mfma_f32_16x16x32_f16(c0, bv3, acc[0][3], 0, 0, 0);
    acc[1][3] = __builtin_amdgcn_mfma_f32_16x16x32_f16(c1, bv3, acc[1][3], 0, 0, 0);
    acc[2][3] = __builtin_amdgcn_mfma_f32_16x16x32_f16(c2, bv3, acc[2][3], 0, 0, 0);
    acc[3][3] = __builtin_amdgcn_mfma_f32_16x16x32_f16(c3, bv3, acc[3][3], 0, 0, 0);
    __builtin_amdgcn_s_setprio(0);

    c0 = n0; c1 = n1; c2 = n2; c3 = n3;
  }

  // epilogue: C/D layout col(q)=lane&15, row(m)=(lane>>4)*4+r
  float* ob = out + (long long)b * COUT * NN * LL;
#pragma unroll
  for (int fr = 0; fr < 4; ++fr) {
#pragma unroll
    for (int r = 0; r < 4; ++r) {
      int m = mt * 64 + fr * 16 + l4 * 4 + r;
      int c = m / 11, l2 = m - c * 11;
      float* orow = ob + (long long)c * NN * LL + l2;
#pragma unroll
      for (int nf = 0; nf < 4; ++nf) {
        int q = q0 + nf * 16;
        orow[(long long)q * LL] = acc[fr][nf][r];
      }
    }
  }
}

// ---------------------------------------------------------------------------
extern "C" void kernel_launch(void* const* d_in, const int* in_sizes, int n_in,
                              void* d_out, int out_size, void* d_ws, size_t ws_size,
                              hipStream_t stream) {
  const float* x  = (const float*)d_in[0];
  const float* w0 = (const float*)d_in[1];
  const float* b0 = (const float*)d_in[2];
  const float* w1 = (const float*)d_in[3];

  float* fbuf = (float*)d_ws;                                   // 16384 f
  float* maxf = fbuf + BB * NN;                                 // 8 f
  float4* tab4 = (float4*)((char*)d_ws + WS_TAB_OFF);           // 16384 float4
  unsigned int* w0pk_g = (unsigned int*)((char*)d_ws + WS_W0PK_OFF);  // 24 KB
  f16* Apan = (f16*)((char*)d_ws + WS_APAN_OFF);                // 23.07 MB

  float* hp  = (float*)d_out;
  float* att = hp + HP_SIZE;

  k_pack<<<dim3(24), dim3(256), 0, stream>>>(w0, w0pk_g);
  k_conv<<<dim3(BB * 256), dim3(512), 0, stream>>>(x, w0pk_g, b0, w1, Apan, fbuf);
  k_maxf<<<dim3(BB), dim3(256), 0, stream>>>(fbuf, maxf);
  k_rowsum<<<dim3(BB * 512), dim3(256), 0, stream>>>(fbuf, maxf, tab4);
  k_gemm<<<dim3(704), dim3(256), 0, stream>>>(Apan, tab4, att, hp);
}

// Round 26
// 138.480 us; speedup vs baseline: 1.1588x; 1.0901x over previous
//
#include <hip/hip_runtime.h>

// Problem constants (fixed by setup_inputs)
#define BB 8
#define CIN 64
#define COUT 64
#define NN 2048
#define TT 13
#define KTT 3
#define LL 11
#define CL 704                         // COUT*LL
#define HP_SIZE 11534336LL             // B*COUT*N*L

// ws layout (bytes): fbuf 65536 | maxf 32 | tab4 262144 | w0frag 24576 | Apan
#define WS_TAB_OFF 65568ULL
#define WS_WFRAG_OFF 327712ULL
#define WS_APAN_OFF 352288ULL

typedef _Float16 f16;
typedef __attribute__((ext_vector_type(8))) _Float16 f16x8;
typedef __attribute__((ext_vector_type(2))) _Float16 f16x2;
typedef __attribute__((ext_vector_type(4))) float f32x4;

__device__ __forceinline__ unsigned int pk16(float a, float b) {
  f16 ha = (f16)a, hb = (f16)b;                    // RTN converts
  unsigned short ua = __builtin_bit_cast(unsigned short, ha);
  unsigned short ub = __builtin_bit_cast(unsigned short, hb);
  return (unsigned int)ua | ((unsigned int)ub << 16);
}
__device__ __forceinline__ f16x2 as_h2(unsigned int u) {
  return __builtin_bit_cast(f16x2, u);
}

// ---------------------------------------------------------------------------
// Kernel 0: build w0 MFMA A-fragments (f16), once.
// w0frag[(s*4+cf)*64 + lane] (f16x8): elem u = (f16)w0[c*192 + k],
//   c = cf*16 + (lane&15), k = s*32 + (lane>>4)*8 + u   (k = ci*3+kt order,
//   which IS w0's natural [c][ci][kt] inner order).
// Same (lane,elem)->(row,k) mapping as the session-verified GEMM A-panels.
// ---------------------------------------------------------------------------
__global__ __launch_bounds__(256) void k_pack2(const float* __restrict__ w0,
                                               f16* __restrict__ w0frag) {
  int t = blockIdx.x * 256 + threadIdx.x;      // 1536 total (6 blocks x 256)
  int lane = t & 63, sc = t >> 6;              // sc 0..23 = s*4+cf
  int s = sc >> 2, cf = sc & 3;
  int l4 = lane >> 4, l15 = lane & 15;
  int c = cf * 16 + l15;
  const float* src = w0 + c * 192 + s * 32 + l4 * 8;
  f16x8 v;
#pragma unroll
  for (int u = 0; u < 8; ++u) v[u] = (f16)src[u];
  *(f16x8*)&w0frag[(long long)t * 8] = v;
}

// ---------------------------------------------------------------------------
// Kernel 1: conv0 as MFMA (im2col). Per wave: one n; 24 x 16x16x32 MFMA
// (M=64 c in 4 frags, N=16 l (11 used), K=192 = 6 steps).
// A (w0) fragments from LDS (conflict-free per-lane b128, 24/wave).
// B built per step: 8 per-lane ds_read_u16 from f16 x-tile (rows pad 18,
// pad zeroed; cols l>=11 computed-but-discarded).
// Epilogue: +bias, f = sum h*w1 (LDS lookups + 64-lane shfl reduce),
// As transpose -> Apan panel write (identical to champion).
// LDS 57344 B -> 2 blocks/CU, 4 waves/SIMD.
// ---------------------------------------------------------------------------
__global__ __launch_bounds__(512, 4) void k_conv(
    const float* __restrict__ x, const f16* __restrict__ w0frag_g,
    const float* __restrict__ b0, const float* __restrict__ w1,
    f16* __restrict__ Apan, float* __restrict__ f) {
  __shared__ __align__(16) f16 wfr[24 * 64 * 8];   // 24576 B  A-fragments
  __shared__ f16 xs16[8 * 64 * 18];                // 18432 B  [n][ci][t pad18]
  __shared__ __align__(16) f16 As[704 * 8];        // 11264 B
  __shared__ float w1s[704];                       //  2816 B
  __shared__ float b0s[64];                        //   256 B  (total 57344)
  const int tid = threadIdx.x;
  const int b = blockIdx.x >> 8;
  const int n0 = (blockIdx.x & 255) << 3;

  // stage w0 fragments: 1536 uint4, coalesced
  {
    const uint4* src = (const uint4*)w0frag_g;
    uint4* dst = (uint4*)wfr;
#pragma unroll
    for (int i = 0; i < 3; ++i) dst[i * 512 + tid] = src[i * 512 + tid];
  }
  // stage w1, b0
  for (int i = tid; i < 704; i += 512) w1s[i] = w1[i];
  if (tid < 64) b0s[tid] = b0[tid];
  // stage x as f16: 64 ci x 104 floats (runs contiguous per ci)
#pragma unroll
  for (int i = 0; i < 13; ++i) {
    int task = i * 512 + tid;                  // 6656 total, exact
    int ci = task / 104, rem = task - ci * 104;
    int n = rem / 13, t2 = rem - n * 13;
    float v = x[(long long)(b * 64 + ci) * 26624 + n0 * 13 + rem];
    xs16[(n * 64 + ci) * 18 + t2] = (f16)v;
  }
  // zero the t=13..17 padding (2560 entries)
  for (int task = tid; task < 2560; task += 512) {
    int p5 = task % 5, rest = task / 5;        // rest = n*64+ci
    xs16[rest * 18 + 13 + p5] = (f16)0.f;
  }
  __syncthreads();

  const int lane = tid & 63, w = tid >> 6;
  const int l4 = lane >> 4, l15 = lane & 15;
  const f16* xn = &xs16[w * 1152];             // this wave's n (64*18 = 1152)

  f32x4 acc[4];
#pragma unroll
  for (int cf = 0; cf < 4; ++cf) acc[cf] = (f32x4){0.f, 0.f, 0.f, 0.f};

#pragma unroll
  for (int s = 0; s < 6; ++s) {
    // B fragment: elem u holds x_im2col[k = s*32 + l4*8 + u][l15]
    int k0 = s * 32 + l4 * 8;
    int ci = k0 / 3, kt = k0 - ci * 3;
    f16x8 bf;
#pragma unroll
    for (int u = 0; u < 8; ++u) {
      bf[u] = xn[ci * 18 + kt + l15];
      ++kt;
      if (kt == 3) { kt = 0; ++ci; }
    }
#pragma unroll
    for (int cf = 0; cf < 4; ++cf) {
      f16x8 af = *(const f16x8*)&wfr[((s * 4 + cf) * 64 + lane) * 8];
      acc[cf] = __builtin_amdgcn_mfma_f32_16x16x32_f16(af, bf, acc[cf], 0, 0, 0);
    }
  }

  // epilogue: bias, f partial (valid cols l15<11), As transpose write
  float p = 0.f;
#pragma unroll
  for (int cf = 0; cf < 4; ++cf) {
#pragma unroll
    for (int r = 0; r < 4; ++r) {
      int c = cf * 16 + l4 * 4 + r;
      float hv = acc[cf][r] + b0s[c];
      if (l15 < 11) {
        p = fmaf(hv, w1s[c * 11 + l15], p);
        As[(c * 11 + l15) * 8 + w] = (f16)hv;
      }
    }
  }
#pragma unroll
  for (int off = 32; off; off >>= 1) p += __shfl_xor(p, off, 64);
  if (lane == 0) f[b * 2048 + n0 + w] = p;
  __syncthreads();

  // panel write: this block covers ks, kgrp, kk = 0..7 (= w dim in As)
  const int ks = n0 >> 5, kgrp = (n0 >> 3) & 3;
#pragma unroll
  for (int i = 0; i < 2; ++i) {
    int m = i * 512 + tid;
    if (m < 704) {
      uint4 v = *(const uint4*)&As[m * 8];     // linear 16B/lane, conflict-free
      int mt = m >> 6, fr = (m >> 4) & 3, r16 = m & 15;
      long long base = ((long long)(b * 11 + mt) * 64 + ks) * 2048 +
                       fr * 512 + (kgrp * 16 + r16) * 8;
      *(uint4*)&Apan[base] = v;
    }
  }
}

// ---------------------------------------------------------------------------
// Kernel 2: per-batch max of f
// ---------------------------------------------------------------------------
__global__ __launch_bounds__(256) void k_maxf(const float* __restrict__ f,
                                              float* __restrict__ maxf) {
  const int b = blockIdx.x, tid = threadIdx.x;
  float m = -1e30f;
  for (int i = tid; i < 2048; i += 256) m = fmaxf(m, f[b * 2048 + i]);
#pragma unroll
  for (int off = 32; off; off >>= 1) m = fmaxf(m, __shfl_xor(m, off, 64));
  __shared__ float red[4];
  if ((tid & 63) == 0) red[tid >> 6] = m;
  __syncthreads();
  if (tid == 0) maxf[b] = fmaxf(fmaxf(red[0], red[1]), fmaxf(red[2], red[3]));
}

// ---------------------------------------------------------------------------
// Kernel 3: softmax row sums + exp-factor table tab4 = (En, E2n, Rq, Sq).
// att[n][q] = max(En_n*Rq_q, E2n_n*Sq_q)  (exact: pos-branch wins iff s>=0)
// ---------------------------------------------------------------------------
__global__ __launch_bounds__(256) void k_rowsum(const float* __restrict__ f,
                                                const float* __restrict__ maxf,
                                                float4* __restrict__ tab4) {
  __shared__ float fs[2048];
  const int b = blockIdx.x >> 9;
  const int q0 = (blockIdx.x & 511) << 2;
  const int tid = threadIdx.x;
#pragma unroll
  for (int i = 0; i < 8; ++i) fs[i * 256 + tid] = f[b * 2048 + i * 256 + tid];
  __syncthreads();
  const int lane = tid & 63, wid = tid >> 6;
  const int q = q0 + wid;
  const float fq = fs[q];
  const float mb = maxf[b];
  float t = fq + mb;
  const float m = t >= 0.f ? t : 0.2f * t;
  float sum = 0.f;
  for (int j = lane; j < 2048; j += 64) {
    float v = fq + fs[j];
    v = v >= 0.f ? v : 0.2f * v;
    sum += __expf(v - m);
  }
#pragma unroll
  for (int off = 32; off; off >>= 1) sum += __shfl_xor(sum, off, 64);
  if (lane == 0) {
    float rq = 1.0f / sum;
    float En = __expf(fq - mb);
    float E2 = __expf(0.2f * fq);
    float Rq = t >= 0.f ? rq : rq * __expf(0.8f * t);
    float Sq = rq * __expf(0.2f * fq - m);
    tab4[b * 2048 + q] = make_float4(En, E2, Rq, Sq);
  }
}

// ---------------------------------------------------------------------------
// Kernel 4: barrier-free 16x16x32 fp16 MFMA GEMM (champion: hoisted B-build
// + single setprio(1) burst of 16 MFMAs; XCD-grouped grid; fused att stores).
// ---------------------------------------------------------------------------
__global__ __launch_bounds__(256, 3) void k_gemm(const f16* __restrict__ Apan,
                                                 const float4* __restrict__ tab4,
                                                 float* __restrict__ att,
                                                 float* __restrict__ out) {
  __shared__ __align__(16) float2 Etab[2048];   // 16 KB, read-only after stage

  const int p = blockIdx.x;
  const int g = p % 88, qt = p / 88;
  const int b = g / 11, mt = g % 11;

  const int tid = threadIdx.x;
  const int qw = tid >> 6, lane = tid & 63;
  const int l15 = lane & 15, l4 = lane >> 4;

  const f16* Ab = Apan + ((long long)(b * 11 + mt) * 64) * 2048 + lane * 8;
  const float4* tb = tab4 + (long long)b * NN;

  // stage Etab (16 KB)
#pragma unroll
  for (int i = 0; i < 8; ++i) {
    int idx = i * 256 + tid;
    float4 v = tb[idx];
    Etab[idx] = make_float2(v.x, v.y);
  }
  // per-nf q-side factors (q fixed per lane per nf)
  const int q0 = qt * 256 + qw * 64 + l15;
  float Rq0, Sq0, Rq1, Sq1, Rq2, Sq2, Rq3, Sq3;
  { float4 t4 = tb[q0];      Rq0 = t4.z; Sq0 = t4.w; }
  { float4 t4 = tb[q0 + 16]; Rq1 = t4.z; Sq1 = t4.w; }
  { float4 t4 = tb[q0 + 32]; Rq2 = t4.z; Sq2 = t4.w; }
  { float4 t4 = tb[q0 + 48]; Rq3 = t4.z; Sq3 = t4.w; }
  __syncthreads();   // Etab ready; ONLY barrier in the kernel

  f32x4 acc[4][4];
#pragma unroll
  for (int fr = 0; fr < 4; ++fr)
#pragma unroll
    for (int nf = 0; nf < 4; ++nf) acc[fr][nf] = (f32x4){0.f, 0.f, 0.f, 0.f};

  // A-load pipeline: current tile in c0..c3, next prefetched into n0..n3
  f16x8 c0 = *(const f16x8*)(Ab);
  f16x8 c1 = *(const f16x8*)(Ab + 512);
  f16x8 c2 = *(const f16x8*)(Ab + 1024);
  f16x8 c3 = *(const f16x8*)(Ab + 1536);

  for (int ks = 0; ks < 64; ++ks) {
    f16x8 n0 = c0, n1 = c1, n2 = c2, n3 = c3;
    if (ks < 63) {
      const f16* at = Ab + (ks + 1) * 2048;
      n0 = *(const f16x8*)(at);
      n1 = *(const f16x8*)(at + 512);
      n2 = *(const f16x8*)(at + 1024);
      n3 = *(const f16x8*)(at + 1536);
    }
    // lane's 8 n-values of the exp-factor table (broadcast within 16-group)
    const int nb = ks * 32 + l4 * 8;
    const float4* ep = (const float4*)&Etab[nb];
    float4 e0 = ep[0], e1 = ep[1], e2 = ep[2], e3 = ep[3];
    float En[8] = {e0.x, e0.z, e1.x, e1.z, e2.x, e2.z, e3.x, e3.z};
    float E2[8] = {e0.y, e0.w, e1.y, e1.w, e2.y, e2.w, e3.y, e3.w};
    const bool owned = ((ks * 11) >> 6) == mt;   // block-uniform
    const long long abase = ((long long)(b * 2048 + nb)) * 2048 + q0;

    // ---- build ALL 4 B fragments (independent chains -> VALU ILP) ----
    f16x8 bv0, bv1, bv2, bv3;
    float vf[4][8];
#pragma unroll
    for (int u = 0; u < 8; ++u) {
      float v0 = fmaxf(En[u] * Rq0, E2[u] * Sq0);
      float v1 = fmaxf(En[u] * Rq1, E2[u] * Sq1);
      float v2 = fmaxf(En[u] * Rq2, E2[u] * Sq2);
      float v3 = fmaxf(En[u] * Rq3, E2[u] * Sq3);
      vf[0][u] = v0; vf[1][u] = v1; vf[2][u] = v2; vf[3][u] = v3;
      bv0[u] = (f16)v0; bv1[u] = (f16)v1; bv2[u] = (f16)v2; bv3[u] = (f16)v3;
    }
    if (owned) {
#pragma unroll
      for (int nf = 0; nf < 4; ++nf) {
        float* ap = att + abase + nf * 16;
#pragma unroll
        for (int u = 0; u < 8; ++u) ap[(long long)u * 2048] = vf[nf][u];
      }
    }
    // ---- 16 back-to-back MFMAs in one prioritized burst ----
    __builtin_amdgcn_s_setprio(1);
    acc[0][0] = __builtin_amdgcn_mfma_f32_16x16x32_f16(c0, bv0, acc[0][0], 0, 0, 0);
    acc[1][0] = __builtin_amdgcn_mfma_f32_16x16x32_f16(c1, bv0, acc[1][0], 0, 0, 0);
    acc[2][0] = __builtin_amdgcn_mfma_f32_16x16x32_f16(c2, bv0, acc[2][0], 0, 0, 0);
    acc[3][0] = __builtin_amdgcn_mfma_f32_16x16x32_f16(c3, bv0, acc[3][0], 0, 0, 0);
    acc[0][1] = __builtin_amdgcn_mfma_f32_16x16x32_f16(c0, bv1, acc[0][1], 0, 0, 0);
    acc[1][1] = __builtin_amdgcn_mfma_f32_16x16x32_f16(c1, bv1, acc[1][1], 0, 0, 0);
    acc[2][1] = __builtin_amdgcn_mfma_f32_16x16x32_f16(c2, bv1, acc[2][1], 0, 0, 0);
    acc[3][1] = __builtin_amdgcn_mfma_f32_16x16x32_f16(c3, bv1, acc[3][1], 0, 0, 0);
    acc[0][2] = __builtin_amdgcn_mfma_f32_16x16x32_f16(c0, bv2, acc[0][2], 0, 0, 0);
    acc[1][2] = __builtin_amdgcn_mfma_f32_16x16x32_f16(c1, bv2, acc[1][2], 0, 0, 0);
    acc[2][2] = __builtin_amdgcn_mfma_f32_16x16x32_f16(c2, bv2, acc[2][2], 0, 0, 0);
    acc[3][2] = __builtin_amdgcn_mfma_f32_16x16x32_f16(c3, bv2, acc[3][2], 0, 0, 0);
    acc[0][3] = __builtin_amdgcn_mfma_f32_16x16x32_f16(c0, bv3, acc[0][3], 0, 0, 0);
    acc[1][3] = __builtin_amdgcn_mfma_f32_16x16x32_f16(c1, bv3, acc[1][3], 0, 0, 0);
    acc[2][3] = __builtin_amdgcn_mfma_f32_16x16x32_f16(c2, bv3, acc[2][3], 0, 0, 0);
    acc[3][3] = __builtin_amdgcn_mfma_f32_16x16x32_f16(c3, bv3, acc[3][3], 0, 0, 0);
    __builtin_amdgcn_s_setprio(0);

    c0 = n0; c1 = n1; c2 = n2; c3 = n3;
  }

  // epilogue: C/D layout col(q)=lane&15, row(m)=(lane>>4)*4+r
  float* ob = out + (long long)b * COUT * NN * LL;
#pragma unroll
  for (int fr = 0; fr < 4; ++fr) {
#pragma unroll
    for (int r = 0; r < 4; ++r) {
      int m = mt * 64 + fr * 16 + l4 * 4 + r;
      int c = m / 11, l2 = m - c * 11;
      float* orow = ob + (long long)c * NN * LL + l2;
#pragma unroll
      for (int nf = 0; nf < 4; ++nf) {
        int q = q0 + nf * 16;
        orow[(long long)q * LL] = acc[fr][nf][r];
      }
    }
  }
}

// ---------------------------------------------------------------------------
extern "C" void kernel_launch(void* const* d_in, const int* in_sizes, int n_in,
                              void* d_out, int out_size, void* d_ws, size_t ws_size,
                              hipStream_t stream) {
  const float* x  = (const float*)d_in[0];
  const float* w0 = (const float*)d_in[1];
  const float* b0 = (const float*)d_in[2];
  const float* w1 = (const float*)d_in[3];

  float* fbuf = (float*)d_ws;                                   // 16384 f
  float* maxf = fbuf + BB * NN;                                 // 8 f
  float4* tab4 = (float4*)((char*)d_ws + WS_TAB_OFF);           // 16384 float4
  f16* w0frag = (f16*)((char*)d_ws + WS_WFRAG_OFF);             // 24 KB
  f16* Apan = (f16*)((char*)d_ws + WS_APAN_OFF);                // 23.07 MB

  float* hp  = (float*)d_out;
  float* att = hp + HP_SIZE;

  k_pack2<<<dim3(6), dim3(256), 0, stream>>>(w0, w0frag);
  k_conv<<<dim3(BB * 256), dim3(512), 0, stream>>>(x, w0frag, b0, w1, Apan, fbuf);
  k_maxf<<<dim3(BB), dim3(256), 0, stream>>>(fbuf, maxf);
  k_rowsum<<<dim3(BB * 512), dim3(256), 0, stream>>>(fbuf, maxf, tab4);
  k_gemm<<<dim3(704), dim3(256), 0, stream>>>(Apan, tab4, att, hp);
}